// Round 7
// baseline (974.346 us; speedup 1.0000x reference)
//
#include <hip/hip_runtime.h>

// DynamicFilterLayerOneChannel:
//   out[n,h,w] = sum_{ky,kx} x[n,h+ky-4,w+kx-4] * F[n,ky*9+kx,h,w] + b[n,h,w]
// v4: stream-consolidation probe. Baseline (4px/thread) holds ~12 loads in
// flight spanning 9-12 distinct 2MB-strided plane streams per wave ->
// ~100-150 concurrent 1KB-granular streams per CU; kernel runs at only
// ~1.65 TB/s (420us) vs 6.3 TB/s achievable. Theory: DRAM/TLB-side cost
// scales with stream count. Fix under test: 16px/thread -> each plane-touch
// is 64B/thread (4x dwordx4), 4KB contiguous per wave; in-flight window
// spans ~3 streams (4x fewer, 4x longer bursts).
// launch_bounds(256,2): VGPR cap 256 (live ~100, no spill risk -- suspected
// failure mode of the 8px attempt at cap 128), 8 waves/CU, 512 blocks =
// exactly 2 blocks/CU. nt load on F restored (round-6 A/B: nt helps ~20us);
// nt store on out. dy-loop rolled to keep the in-flight window compact.

#define KS   9
#define PADV 4
#define NN   4
#define HH   544
#define WW   960
#define G16  (WW / 16)         // 60 groups per row
#define NT   (HH * G16)        // 32640 threads per batch
#define HW   (HH * WW)         // 522240

typedef float vf4 __attribute__((ext_vector_type(4)));

__global__ __launch_bounds__(256, 2) void dynfilter_kernel(
    const float* __restrict__ x,
    const float* __restrict__ filt,
    const float* __restrict__ bias,
    float* __restrict__ out)
{
    const int n = blockIdx.y;                       // wave-uniform batch
    const int p = blockIdx.x * 256 + threadIdx.x;   // pixel-group id
    if (p >= NT) return;                            // 128*256 = 32768 > 32640
    const int g  = p % G16;
    const int h  = p / G16;
    const int w0 = g * 16;

    const float* __restrict__ xb = x + (size_t)n * HW;
    const float* __restrict__ fn = filt + (size_t)n * KS * KS * HW;
    const int off = h * WW + w0;                    // == 16*p, 16B-aligned

    const float* bp = bias + (size_t)n * HW + off;
    vf4 acc0 = *reinterpret_cast<const vf4*>(bp);
    vf4 acc1 = *reinterpret_cast<const vf4*>(bp + 4);
    vf4 acc2 = *reinterpret_cast<const vf4*>(bp + 8);
    vf4 acc3 = *reinterpret_cast<const vf4*>(bp + 12);

    // needs x cols [w0-4, w0+19], rows [h-4, h+4]
    const bool interior = (w0 >= PADV) && (w0 + 19 < WW) &&
                          (h >= PADV) && (h + PADV < HH);

    if (interior) {
        const float* xr = xb + (h - PADV) * WW + (w0 - PADV);
        const float* fp = fn + off;
        #pragma unroll 1
        for (int dy = 0; dy < KS; ++dy) {
            float xrow[24];
            #pragma unroll
            for (int j = 0; j < 6; ++j) {
                vf4 v = *reinterpret_cast<const vf4*>(xr + 4 * j);
                xrow[4 * j + 0] = v.x;
                xrow[4 * j + 1] = v.y;
                xrow[4 * j + 2] = v.z;
                xrow[4 * j + 3] = v.w;
            }
            #pragma unroll
            for (int dx = 0; dx < KS; ++dx) {
                const float* fq = fp + (size_t)dx * HW;
                vf4 f0 = __builtin_nontemporal_load(
                    reinterpret_cast<const vf4*>(fq));
                vf4 f1 = __builtin_nontemporal_load(
                    reinterpret_cast<const vf4*>(fq + 4));
                vf4 f2 = __builtin_nontemporal_load(
                    reinterpret_cast<const vf4*>(fq + 8));
                vf4 f3 = __builtin_nontemporal_load(
                    reinterpret_cast<const vf4*>(fq + 12));
                acc0.x += f0.x * xrow[dx + 0];
                acc0.y += f0.y * xrow[dx + 1];
                acc0.z += f0.z * xrow[dx + 2];
                acc0.w += f0.w * xrow[dx + 3];
                acc1.x += f1.x * xrow[dx + 4];
                acc1.y += f1.y * xrow[dx + 5];
                acc1.z += f1.z * xrow[dx + 6];
                acc1.w += f1.w * xrow[dx + 7];
                acc2.x += f2.x * xrow[dx + 8];
                acc2.y += f2.y * xrow[dx + 9];
                acc2.z += f2.z * xrow[dx + 10];
                acc2.w += f2.w * xrow[dx + 11];
                acc3.x += f3.x * xrow[dx + 12];
                acc3.y += f3.y * xrow[dx + 13];
                acc3.z += f3.z * xrow[dx + 14];
                acc3.w += f3.w * xrow[dx + 15];
            }
            xr += WW;
            fp += (size_t)KS * HW;
        }
    } else {
        const float* fp = fn + off;
        #pragma unroll 1
        for (int dy = 0; dy < KS; ++dy) {
            int row = h + dy - PADV;
            bool rok = (row >= 0) && (row < HH);
            float xrow[24];
            #pragma unroll
            for (int j = 0; j < 24; ++j) {
                int col = w0 - PADV + j;
                bool ok = rok && (col >= 0) && (col < WW);
                xrow[j] = ok ? xb[row * WW + col] : 0.0f;
            }
            #pragma unroll
            for (int dx = 0; dx < KS; ++dx) {
                const float* fq = fp + (size_t)dx * HW;
                vf4 f0 = __builtin_nontemporal_load(
                    reinterpret_cast<const vf4*>(fq));
                vf4 f1 = __builtin_nontemporal_load(
                    reinterpret_cast<const vf4*>(fq + 4));
                vf4 f2 = __builtin_nontemporal_load(
                    reinterpret_cast<const vf4*>(fq + 8));
                vf4 f3 = __builtin_nontemporal_load(
                    reinterpret_cast<const vf4*>(fq + 12));
                acc0.x += f0.x * xrow[dx + 0];
                acc0.y += f0.y * xrow[dx + 1];
                acc0.z += f0.z * xrow[dx + 2];
                acc0.w += f0.w * xrow[dx + 3];
                acc1.x += f1.x * xrow[dx + 4];
                acc1.y += f1.y * xrow[dx + 5];
                acc1.z += f1.z * xrow[dx + 6];
                acc1.w += f1.w * xrow[dx + 7];
                acc2.x += f2.x * xrow[dx + 8];
                acc2.y += f2.y * xrow[dx + 9];
                acc2.z += f2.z * xrow[dx + 10];
                acc2.w += f2.w * xrow[dx + 11];
                acc3.x += f3.x * xrow[dx + 12];
                acc3.y += f3.y * xrow[dx + 13];
                acc3.z += f3.z * xrow[dx + 14];
                acc3.w += f3.w * xrow[dx + 15];
            }
            fp += (size_t)KS * HW;
        }
    }

    float* op = out + (size_t)n * HW + off;
    __builtin_nontemporal_store(acc0, reinterpret_cast<vf4*>(op));
    __builtin_nontemporal_store(acc1, reinterpret_cast<vf4*>(op + 4));
    __builtin_nontemporal_store(acc2, reinterpret_cast<vf4*>(op + 8));
    __builtin_nontemporal_store(acc3, reinterpret_cast<vf4*>(op + 12));
}

extern "C" void kernel_launch(void* const* d_in, const int* in_sizes, int n_in,
                              void* d_out, int out_size, void* d_ws, size_t ws_size,
                              hipStream_t stream) {
    const float* x    = (const float*)d_in[0];  // [4,1,544,960]
    const float* filt = (const float*)d_in[1];  // [4,81,544,960]
    const float* bias = (const float*)d_in[2];  // [4,1,544,960]
    float* out        = (float*)d_out;          // [4,1,544,960]

    dim3 grid((NT + 255) / 256, NN);            // 128 x 4 = 512 blocks = 2/CU
    dynfilter_kernel<<<grid, dim3(256), 0, stream>>>(x, filt, bias, out);
}